// Round 1
// 245.563 us; speedup vs baseline: 1.0402x; 1.0402x over previous
//
#include <hip/hip_runtime.h>

// BoundaryAwareLoss: masked, boundary-weighted BCE over instance channels {1,3,5,7}
// of logits/targets (2,8,128,128,128) fp32.
// 2x 6-neighbor erosion == one erosion by the Manhattan-radius-2 ball (25 pts),
// zero-padded. Targets are binary -> bit-packed erosion (branchless, register-only).
// v5: - zero global atomics: per-block (bce,n) partials -> 256-thread finalize tree
//       (kills the 2048-serialized f64 atomicAdd storm on one cacheline; also removes
//        the ws-zeroing atomicExch ordering hack in pack)
//     - channel-fused main: block = 1/4 z-plane x 4 channels of one batch
//       (wave==channel). pk stencil staged in LDS (5 planes x 36 rows x 4ch,
//       rows padded to 24 B -> 2-way-max bank aliasing == free) and spatial tile
//       staged in LDS (read once instead of once per channel).
//       25 bounds-checked global u64 loads/thread -> ~6 cooperative loads + LDS reads.
//     - pack: 8x work per block (2048 blocks instead of 16384).

#define DD 128
#define HH 128
#define WW 128
#define HW_ (HH * WW)
#define DHW (DD * HH * WW)

typedef unsigned long long ull;

// ws layout (big path): [0 .. 1023] pairs of doubles = per-block partials (16 KB),
//                       packed bits at byte offset 32768 (2 MB).
// ws layout (fallback): ws[0]=sum(bce), ws[1]=sum(n) as doubles.
#define PK_BYTE_OFF 32768
#define NSLOT 1024   // bal_main grid = 512 x 2

// ---------------- pass 1: pack targets (active channels) to 1 bit/voxel ----------------
// pk layout: pk[ch*32768 + row*2 + h], row = z*128+y, h selects x in [64h, 64h+64)
__global__ void __launch_bounds__(256) bal_pack(const float* __restrict__ targets,
                                                const int*   __restrict__ mask,
                                                ull*         __restrict__ pk)
{
    const int ch = blockIdx.y;           // 0..7
    const int b  = ch >> 2;
    const int c  = (ch & 3) * 2 + 1;     // instance channels 1,3,5,7
    if (mask[b * 8 + c] == 0) return;

    const int tid = threadIdx.x;
    const size_t blockbase = (size_t)blockIdx.x * 8192;   // voxels
    const float* tg  = targets + (size_t)(b * 8 + c) * DHW + blockbase;
    ull*         pko = pk + (size_t)ch * 32768 + (blockbase >> 6);

    #pragma unroll
    for (int k = 0; k < 8; ++k) {
        float4 t4 = *(const float4*)(tg + k * 1024 + tid * 4);
        unsigned nib = (unsigned)(t4.x > 0.5f)
                     | ((unsigned)(t4.y > 0.5f) << 1)
                     | ((unsigned)(t4.z > 0.5f) << 2)
                     | ((unsigned)(t4.w > 0.5f) << 3);
        ull v = ((ull)nib) << ((tid & 15) * 4);
        // OR-combine nibbles across each aligned group of 16 lanes -> one u64 (64 voxels)
        v |= __shfl_xor(v, 1);
        v |= __shfl_xor(v, 2);
        v |= __shfl_xor(v, 4);
        v |= __shfl_xor(v, 8);
        if ((tid & 15) == 0)
            pko[k * 16 + (tid >> 4)] = v;
    }
}

// ---------------- pass 2: erosion (bitwise, LDS-staged) + BCE + per-block partial ----------------
// grid (512, 2): blockIdx.y = batch, blockIdx.x -> (z = bx>>2, y0 = (bx&3)*32).
// Block covers 32 y-rows of one z-plane for ALL 4 instance channels of the batch.
// wave w (0..3) owns channel 2w+1; lane l owns local half-row l (row l>>1, half l&1).
__global__ void __launch_bounds__(256) bal_main(const float* __restrict__ logits,
                                                const float* __restrict__ spatial,
                                                const int*   __restrict__ mask,
                                                const ull*   __restrict__ pk,
                                                double*      __restrict__ pr)
{
    const int b   = blockIdx.y;
    const int bx  = blockIdx.x;
    const int z   = bx >> 2;
    const int y0  = (bx & 3) * 32;
    const int tid = threadIdx.x;
    const int wave = tid >> 6;
    const int lane = tid & 63;
    const int sid  = b * 512 + bx;       // partial slot

    const int m0 = mask[b * 8 + 1], m1 = mask[b * 8 + 3];
    const int m2 = mask[b * 8 + 5], m3 = mask[b * 8 + 7];
    if ((m0 | m1 | m2 | m3) == 0) {
        if (tid == 0) { pr[2 * sid] = 0.0; pr[2 * sid + 1] = 0.0; }
        return;
    }

    // rows padded to 3 u64 (24 B): stencil reads stride 24 B -> <=2-way bank alias (free)
    __shared__ ull   tile[4][5][36][3];   // 17,280 B ([2] never touched)
    __shared__ float sp[4096];            // 16,384 B: spatial for this (z, y0..y0+31)
    __shared__ float sb[4], sn[4];

    // ---- cooperative stage: pk stencil (4 ch x 5 z-planes x 36 y-rows x 2) ----
    for (int idx = tid; idx < 1440; idx += 256) {
        const int ch  = idx / 360;
        int rem       = idx - ch * 360;
        const int dz  = rem / 72;
        rem          -= dz * 72;           // = rowl*2 + h
        const int rowl = rem >> 1;
        const int h    = rem & 1;
        const int zz = z + dz - 2;
        const int yy = y0 + rowl - 2;
        ull v = 0ull;
        if (((unsigned)zz < 128u) & ((unsigned)yy < 128u))
            v = pk[(size_t)(b * 4 + ch) * 32768 + (size_t)(((zz << 7) + yy) << 1) + h];
        tile[ch][dz][rowl][h] = v;
    }
    // ---- cooperative stage: spatial tile (4096 floats, contiguous) ----
    const int gbase = z * HW_ + y0 * WW;
    const float* spg = spatial + (size_t)b * DHW + gbase;
    #pragma unroll
    for (int k = 0; k < 4; ++k) {
        const int f = (tid + k * 256) * 4;
        *(float4*)(sp + f) = *(const float4*)(spg + f);
    }
    __syncthreads();

    const int act = (wave == 0) ? m0 : (wave == 1) ? m1 : (wave == 2) ? m2 : m3;

    float acc = 0.0f, n = 0.0f;
    if (act) {
        // ---- branchless 25-pt erosion on 128-bit rows, sourced from LDS ----
        const int rl = (lane >> 1) + 2;    // local row in tile, [2..33]
        const int h  = lane & 1;
        ull c0 = tile[wave][2][rl][0];
        ull c1 = tile[wave][2][rl][1];
        // center row: x-erosion radius 2
        ull elo = c0 & ((c0 >> 1) | (c1 << 63)) & (c0 << 1)
                     & ((c0 >> 2) | (c1 << 62)) & (c0 << 2);
        ull ehi = c1 & (c1 >> 1) & ((c1 << 1) | (c0 >> 63))
                     & (c1 >> 2) & ((c1 << 2) | (c0 >> 62));
        // Manhattan-dist-1 rows: radius 1
        {
            ull a0, a1;
            a0 = tile[wave][1][rl][0]; a1 = tile[wave][1][rl][1];        // z-1
            elo &= a0 & ((a0 >> 1) | (a1 << 63)) & (a0 << 1);
            ehi &= a1 & (a1 >> 1) & ((a1 << 1) | (a0 >> 63));
            a0 = tile[wave][3][rl][0]; a1 = tile[wave][3][rl][1];        // z+1
            elo &= a0 & ((a0 >> 1) | (a1 << 63)) & (a0 << 1);
            ehi &= a1 & (a1 >> 1) & ((a1 << 1) | (a0 >> 63));
            a0 = tile[wave][2][rl - 1][0]; a1 = tile[wave][2][rl - 1][1]; // y-1
            elo &= a0 & ((a0 >> 1) | (a1 << 63)) & (a0 << 1);
            ehi &= a1 & (a1 >> 1) & ((a1 << 1) | (a0 >> 63));
            a0 = tile[wave][2][rl + 1][0]; a1 = tile[wave][2][rl + 1][1]; // y+1
            elo &= a0 & ((a0 >> 1) | (a1 << 63)) & (a0 << 1);
            ehi &= a1 & (a1 >> 1) & ((a1 << 1) | (a0 >> 63));
        }
        // Manhattan-dist-2 rows: radius 0
        {
            ull a0, a1;
            a0 = tile[wave][0][rl][0];     a1 = tile[wave][0][rl][1];     elo &= a0; ehi &= a1; // z-2
            a0 = tile[wave][4][rl][0];     a1 = tile[wave][4][rl][1];     elo &= a0; ehi &= a1; // z+2
            a0 = tile[wave][2][rl - 2][0]; a1 = tile[wave][2][rl - 2][1]; elo &= a0; ehi &= a1; // y-2
            a0 = tile[wave][2][rl + 2][0]; a1 = tile[wave][2][rl + 2][1]; elo &= a0; ehi &= a1; // y+2
            a0 = tile[wave][1][rl - 1][0]; a1 = tile[wave][1][rl - 1][1]; elo &= a0; ehi &= a1; // z-1,y-1
            a0 = tile[wave][1][rl + 1][0]; a1 = tile[wave][1][rl + 1][1]; elo &= a0; ehi &= a1; // z-1,y+1
            a0 = tile[wave][3][rl - 1][0]; a1 = tile[wave][3][rl - 1][1]; elo &= a0; ehi &= a1; // z+1,y-1
            a0 = tile[wave][3][rl + 1][0]; a1 = tile[wave][3][rl + 1][1]; elo &= a0; ehi &= a1; // z+1,y+1
        }
        const ull ero   = h ? ehi : elo;
        const ull tbits = h ? c1  : c0;

        // ---- BCE: wave streams its channel's 4096 voxels; spatial from LDS ----
        const int c = wave * 2 + 1;
        const float* lg = logits + (size_t)(b * 8 + c) * DHW + gbase;

        #pragma unroll 4
        for (int m = 0; m < 16; ++m) {
            const int q   = 4 * m + (lane >> 4);      // local half-row served this step
            const ull er  = __shfl(ero, q);
            const ull tb  = __shfl(tbits, q);
            const int sh  = (lane & 15) * 4;
            const unsigned eb  = (unsigned)(er >> sh) & 0xFu;
            const unsigned tbn = (unsigned)(tb >> sh) & 0xFu;
            const int voff = q * 64 + sh;             // == 256*m + 4*lane (contiguous)
            const float4 l4 = *(const float4*)(lg + voff);
            const float4 s4 = *(const float4*)(sp + voff);
            #define PROC(LV, SV, TB, EB)                                              \
            {                                                                         \
                const float tf = (float)(TB);                                         \
                const float w  = fmaf(4.0f, tf - (float)(EB), 1.0f);                  \
                const float a  = fabsf(LV);                                           \
                const float u  = __builtin_amdgcn_exp2f(a * -1.4426950408889634f);    \
                const float so = __builtin_amdgcn_logf(1.0f + u) * 0.6931471805599453f;\
                const float bce = fmaxf(LV, 0.0f) - (LV) * tf + so;                   \
                acc = fmaf((SV) * w, bce, acc);                                       \
                n += (SV);                                                            \
            }
            PROC(l4.x, s4.x, tbn & 1u,        eb & 1u)
            PROC(l4.y, s4.y, (tbn >> 1) & 1u, (eb >> 1) & 1u)
            PROC(l4.z, s4.z, (tbn >> 2) & 1u, (eb >> 2) & 1u)
            PROC(l4.w, s4.w, (tbn >> 3) & 1u, (eb >> 3) & 1u)
            #undef PROC
        }
    }

    // wave (64-lane) shuffle reduction
    #pragma unroll
    for (int o = 32; o > 0; o >>= 1) {
        acc += __shfl_down(acc, o);
        n   += __shfl_down(n, o);
    }
    if (lane == 0) { sb[wave] = acc; sn[wave] = n; }
    __syncthreads();
    if (tid == 0) {
        pr[2 * sid]     = (double)(sb[0] + sb[1] + sb[2] + sb[3]);
        pr[2 * sid + 1] = (double)(sn[0] + sn[1] + sn[2] + sn[3]);
    }
}

// ---------------- pass 3: tree-reduce the 1024 partials (no atomics anywhere) ----------------
__global__ void __launch_bounds__(256) bal_finalize(const double* __restrict__ pr,
                                                    float* __restrict__ out)
{
    double s = 0.0, n = 0.0;
    for (int i = threadIdx.x; i < NSLOT; i += 256) {
        s += pr[2 * i];
        n += pr[2 * i + 1];
    }
    #pragma unroll
    for (int o = 32; o > 0; o >>= 1) {
        s += __shfl_down(s, o);
        n += __shfl_down(n, o);
    }
    __shared__ double ss[4], nn[4];
    const int wave = threadIdx.x >> 6;
    if ((threadIdx.x & 63) == 0) { ss[wave] = s; nn[wave] = n; }
    __syncthreads();
    if (threadIdx.x == 0) {
        const double S = ss[0] + ss[1] + ss[2] + ss[3];
        const double N = nn[0] + nn[1] + nn[2] + nn[3];
        out[0] = (N > 0.0) ? (float)(S / (N < 1.0 ? 1.0 : N)) : 0.0f;
    }
}

// ---------------- fallback (ws too small): round-1 direct kernel ----------------
__device__ __constant__ signed char OFFS[24][3] = {
    {-1,0,0},{1,0,0},{0,-1,0},{0,1,0},{0,0,-1},{0,0,1},
    {-2,0,0},{2,0,0},{0,-2,0},{0,2,0},{0,0,-2},{0,0,2},
    {-1,-1,0},{-1,1,0},{1,-1,0},{1,1,0},
    {-1,0,-1},{-1,0,1},{1,0,-1},{1,0,1},
    {0,-1,-1},{0,-1,1},{0,1,-1},{0,1,1}
};

__global__ void __launch_bounds__(256) bal_direct(
    const float* __restrict__ logits, const float* __restrict__ targets,
    const int* __restrict__ mask, const float* __restrict__ spatial,
    double* __restrict__ ws)
{
    const int ch = blockIdx.y;
    const int b  = ch >> 2;
    const int c  = 2 * (ch & 3) + 1;
    if (mask[b * 8 + c] == 0) return;
    const float* lg = logits  + (size_t)(b * 8 + c) * DHW;
    const float* tg = targets + (size_t)(b * 8 + c) * DHW;
    const float* sp = spatial + (size_t)b * DHW;
    const int tid = threadIdx.x;
    const int row = blockIdx.x * 8 + (tid >> 5);
    const int x0  = (tid & 31) * 4;
    const int z   = row >> 7;
    const int y   = row & 127;
    const size_t off = (size_t)row * WW + x0;
    float4 s4 = *(const float4*)(sp + off);
    float n_local   = s4.x + s4.y + s4.z + s4.w;
    float bce_local = 0.0f;
    if (n_local > 0.0f) {
        float4 l4 = *(const float4*)(lg + off);
        float4 t4 = *(const float4*)(tg + off);
        const float sv[4] = {s4.x, s4.y, s4.z, s4.w};
        const float lv[4] = {l4.x, l4.y, l4.z, l4.w};
        const float tv[4] = {t4.x, t4.y, t4.z, t4.w};
        #pragma unroll
        for (int j = 0; j < 4; ++j) {
            if (sv[j] == 0.0f) continue;
            const float l = lv[j];
            const float t = tv[j];
            float bce = fmaxf(l, 0.0f) - l * t + log1pf(expf(-fabsf(l)));
            float w = 1.0f;
            if (t > 0.5f) {
                float e = 1.0f;
                const int x = x0 + j;
                for (int k = 0; k < 24; ++k) {
                    const int zz = z + OFFS[k][0];
                    const int yy = y + OFFS[k][1];
                    const int xx = x + OFFS[k][2];
                    float v = 0.0f;
                    if (((unsigned)zz < 128u) & ((unsigned)yy < 128u) & ((unsigned)xx < 128u))
                        v = tg[zz * HW_ + yy * WW + xx];
                    if (v < 0.5f) { e = 0.0f; break; }
                }
                w = 1.0f + 4.0f * (1.0f - e);
            }
            bce_local += bce * w;
        }
    }
    #pragma unroll
    for (int o = 32; o > 0; o >>= 1) {
        bce_local += __shfl_down(bce_local, o);
        n_local   += __shfl_down(n_local, o);
    }
    __shared__ float sb[4], sn[4];
    const int wave = tid >> 6;
    if ((tid & 63) == 0) { sb[wave] = bce_local; sn[wave] = n_local; }
    __syncthreads();
    if (tid == 0) {
        atomicAdd(&ws[0], (double)(sb[0] + sb[1] + sb[2] + sb[3]));
        atomicAdd(&ws[1], (double)(sn[0] + sn[1] + sn[2] + sn[3]));
    }
}

__global__ void bal_finalize_ws(const double* __restrict__ ws, float* __restrict__ out)
{
    const double s = ws[0];
    const double n = ws[1];
    out[0] = (n > 0.0) ? (float)(s / (n < 1.0 ? 1.0 : n)) : 0.0f;
}

extern "C" void kernel_launch(void* const* d_in, const int* in_sizes, int n_in,
                              void* d_out, int out_size, void* d_ws, size_t ws_size,
                              hipStream_t stream)
{
    const float* logits  = (const float*)d_in[0];
    const float* targets = (const float*)d_in[1];
    const int*   mask    = (const int*)d_in[2];
    const float* spatial = (const float*)d_in[3];

    const size_t need = PK_BYTE_OFF + (size_t)8 * 32768 * sizeof(ull); // partials + 2 MB bits
    if (ws_size >= need) {
        ull*    pk = (ull*)((char*)d_ws + PK_BYTE_OFF);
        double* pr = (double*)d_ws;
        bal_pack<<<dim3(256, 8), 256, 0, stream>>>(targets, mask, pk);
        bal_main<<<dim3(512, 2), 256, 0, stream>>>(logits, spatial, mask, pk, pr);
        bal_finalize<<<1, 256, 0, stream>>>(pr, (float*)d_out);
    } else {
        double* ws = (double*)d_ws;
        hipMemsetAsync(d_ws, 0, 16, stream);
        bal_direct<<<dim3(2048, 8), 256, 0, stream>>>(logits, targets, mask, spatial, ws);
        bal_finalize_ws<<<1, 1, 0, stream>>>(ws, (float*)d_out);
    }
}

// Round 2
// 243.340 us; speedup vs baseline: 1.0497x; 1.0091x over previous
//
#include <hip/hip_runtime.h>
#include <hip/hip_cooperative_groups.h>

// BoundaryAwareLoss: masked, boundary-weighted BCE over instance channels {1,3,5,7}
// of logits/targets (2,8,128,128,128) fp32.
// 2x 6-neighbor erosion == one erosion by the Manhattan-radius-2 ball (25 pts),
// zero-padded. Targets are binary -> bit-packed erosion (branchless, register-only).
// v6: single cooperative kernel (pack -> grid.sync -> main -> grid.sync -> finalize).
//     Removes 2 kernel launches + 2 full inter-dispatch drains; pk stays L2-hot.
//     1024 blocks x 256 thr = 4 blocks/CU x 256 CU co-resident
//     (__launch_bounds__(256,4): LDS 34KB*4=136KB<=160KB, VGPR<=128).
//     Fallbacks: 3-kernel v5 path (no coop support), bal_direct (ws too small).

#define DD 128
#define HH 128
#define WW 128
#define HW_ (HH * WW)
#define DHW (DD * HH * WW)

typedef unsigned long long ull;

namespace cg = cooperative_groups;

// ws layout (big path): [0 .. 1023] pairs of doubles = per-block partials (16 KB),
//                       packed bits at byte offset 32768 (2 MB).
// ws layout (fallback): ws[0]=sum(bce), ws[1]=sum(n) as doubles.
#define PK_BYTE_OFF 32768
#define NSLOT 1024

// ---------------- shared phase bodies ----------------

// pack 1024 voxels/iter (256 thr x float4); 16-lane OR-combine -> one u64 per 64 voxels
__device__ __forceinline__ void pack_chunk(const float* __restrict__ tg,
                                           ull* __restrict__ pko,
                                           int tid, int k)
{
    float4 t4 = *(const float4*)(tg + k * 1024 + tid * 4);
    unsigned nib = (unsigned)(t4.x > 0.5f)
                 | ((unsigned)(t4.y > 0.5f) << 1)
                 | ((unsigned)(t4.z > 0.5f) << 2)
                 | ((unsigned)(t4.w > 0.5f) << 3);
    ull v = ((ull)nib) << ((tid & 15) * 4);
    v |= __shfl_xor(v, 1);
    v |= __shfl_xor(v, 2);
    v |= __shfl_xor(v, 4);
    v |= __shfl_xor(v, 8);
    if ((tid & 15) == 0)
        pko[k * 16 + (tid >> 4)] = v;
}

// v5-proven main tile body: block = 1/4 z-plane x 4 channels of one batch.
// wave w owns channel 2w+1; lane l owns local half-row l. NO early returns
// (callers may need to reach a grid barrier afterwards).
__device__ __forceinline__ void main_tile_body(const float* __restrict__ logits,
                                               const float* __restrict__ spatial,
                                               const int*   __restrict__ mask,
                                               const ull*   __restrict__ pk,
                                               double*      __restrict__ pr,
                                               int b, int bx)
{
    const int z    = bx >> 2;
    const int y0   = (bx & 3) * 32;
    const int tid  = threadIdx.x;
    const int wave = tid >> 6;
    const int lane = tid & 63;
    const int sid  = b * 512 + bx;       // partial slot

    const int m0 = mask[b * 8 + 1], m1 = mask[b * 8 + 3];
    const int m2 = mask[b * 8 + 5], m3 = mask[b * 8 + 7];
    const int anyact = m0 | m1 | m2 | m3;

    // rows padded to 3 u64 (24 B): stencil reads stride 24 B -> <=2-way bank alias (free)
    __shared__ ull   tile[4][5][36][3];   // 17,280 B ([2] never touched)
    __shared__ float sp[4096];            // 16,384 B: spatial for this (z, y0..y0+31)
    __shared__ float sb[4], sn[4];

    const int gbase = z * HW_ + y0 * WW;

    if (anyact) {
        // ---- cooperative stage: pk stencil (4 ch x 5 z-planes x 36 y-rows x 2) ----
        for (int idx = tid; idx < 1440; idx += 256) {
            const int ch  = idx / 360;
            int rem       = idx - ch * 360;
            const int dz  = rem / 72;
            rem          -= dz * 72;           // = rowl*2 + h
            const int rowl = rem >> 1;
            const int h    = rem & 1;
            const int zz = z + dz - 2;
            const int yy = y0 + rowl - 2;
            ull v = 0ull;
            if (((unsigned)zz < 128u) & ((unsigned)yy < 128u))
                v = pk[(size_t)(b * 4 + ch) * 32768 + (size_t)(((zz << 7) + yy) << 1) + h];
            tile[ch][dz][rowl][h] = v;
        }
        // ---- cooperative stage: spatial tile (4096 floats, contiguous) ----
        const float* spg = spatial + (size_t)b * DHW + gbase;
        #pragma unroll
        for (int k = 0; k < 4; ++k) {
            const int f = (tid + k * 256) * 4;
            *(float4*)(sp + f) = *(const float4*)(spg + f);
        }
    }
    __syncthreads();

    const int act = anyact ? ((wave == 0) ? m0 : (wave == 1) ? m1 : (wave == 2) ? m2 : m3) : 0;

    float acc = 0.0f, n = 0.0f;
    if (act) {
        // ---- branchless 25-pt erosion on 128-bit rows, sourced from LDS ----
        const int rl = (lane >> 1) + 2;    // local row in tile, [2..33]
        const int h  = lane & 1;
        ull c0 = tile[wave][2][rl][0];
        ull c1 = tile[wave][2][rl][1];
        // center row: x-erosion radius 2
        ull elo = c0 & ((c0 >> 1) | (c1 << 63)) & (c0 << 1)
                     & ((c0 >> 2) | (c1 << 62)) & (c0 << 2);
        ull ehi = c1 & (c1 >> 1) & ((c1 << 1) | (c0 >> 63))
                     & (c1 >> 2) & ((c1 << 2) | (c0 >> 62));
        // Manhattan-dist-1 rows: radius 1
        {
            ull a0, a1;
            a0 = tile[wave][1][rl][0]; a1 = tile[wave][1][rl][1];        // z-1
            elo &= a0 & ((a0 >> 1) | (a1 << 63)) & (a0 << 1);
            ehi &= a1 & (a1 >> 1) & ((a1 << 1) | (a0 >> 63));
            a0 = tile[wave][3][rl][0]; a1 = tile[wave][3][rl][1];        // z+1
            elo &= a0 & ((a0 >> 1) | (a1 << 63)) & (a0 << 1);
            ehi &= a1 & (a1 >> 1) & ((a1 << 1) | (a0 >> 63));
            a0 = tile[wave][2][rl - 1][0]; a1 = tile[wave][2][rl - 1][1]; // y-1
            elo &= a0 & ((a0 >> 1) | (a1 << 63)) & (a0 << 1);
            ehi &= a1 & (a1 >> 1) & ((a1 << 1) | (a0 >> 63));
            a0 = tile[wave][2][rl + 1][0]; a1 = tile[wave][2][rl + 1][1]; // y+1
            elo &= a0 & ((a0 >> 1) | (a1 << 63)) & (a0 << 1);
            ehi &= a1 & (a1 >> 1) & ((a1 << 1) | (a0 >> 63));
        }
        // Manhattan-dist-2 rows: radius 0
        {
            ull a0, a1;
            a0 = tile[wave][0][rl][0];     a1 = tile[wave][0][rl][1];     elo &= a0; ehi &= a1; // z-2
            a0 = tile[wave][4][rl][0];     a1 = tile[wave][4][rl][1];     elo &= a0; ehi &= a1; // z+2
            a0 = tile[wave][2][rl - 2][0]; a1 = tile[wave][2][rl - 2][1]; elo &= a0; ehi &= a1; // y-2
            a0 = tile[wave][2][rl + 2][0]; a1 = tile[wave][2][rl + 2][1]; elo &= a0; ehi &= a1; // y+2
            a0 = tile[wave][1][rl - 1][0]; a1 = tile[wave][1][rl - 1][1]; elo &= a0; ehi &= a1; // z-1,y-1
            a0 = tile[wave][1][rl + 1][0]; a1 = tile[wave][1][rl + 1][1]; elo &= a0; ehi &= a1; // z-1,y+1
            a0 = tile[wave][3][rl - 1][0]; a1 = tile[wave][3][rl - 1][1]; elo &= a0; ehi &= a1; // z+1,y-1
            a0 = tile[wave][3][rl + 1][0]; a1 = tile[wave][3][rl + 1][1]; elo &= a0; ehi &= a1; // z+1,y+1
        }
        const ull ero   = h ? ehi : elo;
        const ull tbits = h ? c1  : c0;

        // ---- BCE: wave streams its channel's 4096 voxels; spatial from LDS ----
        const int c = wave * 2 + 1;
        const float* lg = logits + (size_t)(b * 8 + c) * DHW + gbase;

        #pragma unroll 4
        for (int m = 0; m < 16; ++m) {
            const int q   = 4 * m + (lane >> 4);      // local half-row served this step
            const ull er  = __shfl(ero, q);
            const ull tb  = __shfl(tbits, q);
            const int sh  = (lane & 15) * 4;
            const unsigned eb  = (unsigned)(er >> sh) & 0xFu;
            const unsigned tbn = (unsigned)(tb >> sh) & 0xFu;
            const int voff = q * 64 + sh;             // == 256*m + 4*lane (contiguous)
            const float4 l4 = *(const float4*)(lg + voff);
            const float4 s4 = *(const float4*)(sp + voff);
            #define PROC(LV, SV, TB, EB)                                              \
            {                                                                         \
                const float tf = (float)(TB);                                         \
                const float w  = fmaf(4.0f, tf - (float)(EB), 1.0f);                  \
                const float a  = fabsf(LV);                                           \
                const float u  = __builtin_amdgcn_exp2f(a * -1.4426950408889634f);    \
                const float so = __builtin_amdgcn_logf(1.0f + u) * 0.6931471805599453f;\
                const float bce = fmaxf(LV, 0.0f) - (LV) * tf + so;                   \
                acc = fmaf((SV) * w, bce, acc);                                       \
                n += (SV);                                                            \
            }
            PROC(l4.x, s4.x, tbn & 1u,        eb & 1u)
            PROC(l4.y, s4.y, (tbn >> 1) & 1u, (eb >> 1) & 1u)
            PROC(l4.z, s4.z, (tbn >> 2) & 1u, (eb >> 2) & 1u)
            PROC(l4.w, s4.w, (tbn >> 3) & 1u, (eb >> 3) & 1u)
            #undef PROC
        }
    }

    // wave (64-lane) shuffle reduction
    #pragma unroll
    for (int o = 32; o > 0; o >>= 1) {
        acc += __shfl_down(acc, o);
        n   += __shfl_down(n, o);
    }
    if (lane == 0) { sb[wave] = acc; sn[wave] = n; }
    __syncthreads();
    if (tid == 0) {
        pr[2 * sid]     = (double)(sb[0] + sb[1] + sb[2] + sb[3]);
        pr[2 * sid + 1] = (double)(sn[0] + sn[1] + sn[2] + sn[3]);
    }
}

// ---------------- v6: single cooperative kernel ----------------
__global__ void __launch_bounds__(256, 4) bal_fused(const float* __restrict__ logits,
                                                    const float* __restrict__ targets,
                                                    const float* __restrict__ spatial,
                                                    const int*   __restrict__ mask,
                                                    ull*         __restrict__ pk,
                                                    double*      __restrict__ pr,
                                                    float*       __restrict__ out)
{
    cg::grid_group grid = cg::this_grid();
    const int gid = blockIdx.x;          // 0..1023
    const int tid = threadIdx.x;

    // ---- phase A: pack (128 blocks per channel, 16384 voxels/block) ----
    {
        const int ch = gid >> 7;             // 0..7
        const int b  = ch >> 2;
        const int c  = (ch & 3) * 2 + 1;
        if (mask[b * 8 + c] != 0) {
            const size_t blockbase = (size_t)(gid & 127) * 16384;
            const float* tg  = targets + (size_t)(b * 8 + c) * DHW + blockbase;
            ull*         pko = pk + (size_t)ch * 32768 + (blockbase >> 6);
            #pragma unroll
            for (int k = 0; k < 16; ++k)
                pack_chunk(tg, pko, tid, k);
        }
    }
    grid.sync();

    // ---- phase B: erosion + BCE + per-block partial ----
    main_tile_body(logits, spatial, mask, pk, pr, gid >> 9, gid & 511);
    grid.sync();

    // ---- phase C: block 0 tree-reduces the 1024 partials ----
    if (gid == 0) {
        double s = 0.0, n = 0.0;
        for (int i = tid; i < NSLOT; i += 256) {
            s += pr[2 * i];
            n += pr[2 * i + 1];
        }
        #pragma unroll
        for (int o = 32; o > 0; o >>= 1) {
            s += __shfl_down(s, o);
            n += __shfl_down(n, o);
        }
        __shared__ double ss[4], nn[4];
        const int wave = tid >> 6;
        if ((tid & 63) == 0) { ss[wave] = s; nn[wave] = n; }
        __syncthreads();
        if (tid == 0) {
            const double S = ss[0] + ss[1] + ss[2] + ss[3];
            const double N = nn[0] + nn[1] + nn[2] + nn[3];
            out[0] = (N > 0.0) ? (float)(S / (N < 1.0 ? 1.0 : N)) : 0.0f;
        }
    }
}

// ---------------- fallback: 3-kernel v5 path ----------------
__global__ void __launch_bounds__(256) bal_pack(const float* __restrict__ targets,
                                                const int*   __restrict__ mask,
                                                ull*         __restrict__ pk)
{
    const int ch = blockIdx.y;
    const int b  = ch >> 2;
    const int c  = (ch & 3) * 2 + 1;
    if (mask[b * 8 + c] == 0) return;
    const int tid = threadIdx.x;
    const size_t blockbase = (size_t)blockIdx.x * 8192;
    const float* tg  = targets + (size_t)(b * 8 + c) * DHW + blockbase;
    ull*         pko = pk + (size_t)ch * 32768 + (blockbase >> 6);
    #pragma unroll
    for (int k = 0; k < 8; ++k)
        pack_chunk(tg, pko, tid, k);
}

__global__ void __launch_bounds__(256) bal_main(const float* __restrict__ logits,
                                                const float* __restrict__ spatial,
                                                const int*   __restrict__ mask,
                                                const ull*   __restrict__ pk,
                                                double*      __restrict__ pr)
{
    main_tile_body(logits, spatial, mask, pk, pr, blockIdx.y, blockIdx.x);
}

__global__ void __launch_bounds__(256) bal_finalize(const double* __restrict__ pr,
                                                    float* __restrict__ out)
{
    double s = 0.0, n = 0.0;
    for (int i = threadIdx.x; i < NSLOT; i += 256) {
        s += pr[2 * i];
        n += pr[2 * i + 1];
    }
    #pragma unroll
    for (int o = 32; o > 0; o >>= 1) {
        s += __shfl_down(s, o);
        n += __shfl_down(n, o);
    }
    __shared__ double ss[4], nn[4];
    const int wave = threadIdx.x >> 6;
    if ((threadIdx.x & 63) == 0) { ss[wave] = s; nn[wave] = n; }
    __syncthreads();
    if (threadIdx.x == 0) {
        const double S = ss[0] + ss[1] + ss[2] + ss[3];
        const double N = nn[0] + nn[1] + nn[2] + nn[3];
        out[0] = (N > 0.0) ? (float)(S / (N < 1.0 ? 1.0 : N)) : 0.0f;
    }
}

// ---------------- fallback (ws too small): round-1 direct kernel ----------------
__device__ __constant__ signed char OFFS[24][3] = {
    {-1,0,0},{1,0,0},{0,-1,0},{0,1,0},{0,0,-1},{0,0,1},
    {-2,0,0},{2,0,0},{0,-2,0},{0,2,0},{0,0,-2},{0,0,2},
    {-1,-1,0},{-1,1,0},{1,-1,0},{1,1,0},
    {-1,0,-1},{-1,0,1},{1,0,-1},{1,0,1},
    {0,-1,-1},{0,-1,1},{0,1,-1},{0,1,1}
};

__global__ void __launch_bounds__(256) bal_direct(
    const float* __restrict__ logits, const float* __restrict__ targets,
    const int* __restrict__ mask, const float* __restrict__ spatial,
    double* __restrict__ ws)
{
    const int ch = blockIdx.y;
    const int b  = ch >> 2;
    const int c  = 2 * (ch & 3) + 1;
    if (mask[b * 8 + c] == 0) return;
    const float* lg = logits  + (size_t)(b * 8 + c) * DHW;
    const float* tg = targets + (size_t)(b * 8 + c) * DHW;
    const float* sp = spatial + (size_t)b * DHW;
    const int tid = threadIdx.x;
    const int row = blockIdx.x * 8 + (tid >> 5);
    const int x0  = (tid & 31) * 4;
    const int z   = row >> 7;
    const int y   = row & 127;
    const size_t off = (size_t)row * WW + x0;
    float4 s4 = *(const float4*)(sp + off);
    float n_local   = s4.x + s4.y + s4.z + s4.w;
    float bce_local = 0.0f;
    if (n_local > 0.0f) {
        float4 l4 = *(const float4*)(lg + off);
        float4 t4 = *(const float4*)(tg + off);
        const float sv[4] = {s4.x, s4.y, s4.z, s4.w};
        const float lv[4] = {l4.x, l4.y, l4.z, l4.w};
        const float tv[4] = {t4.x, t4.y, t4.z, t4.w};
        #pragma unroll
        for (int j = 0; j < 4; ++j) {
            if (sv[j] == 0.0f) continue;
            const float l = lv[j];
            const float t = tv[j];
            float bce = fmaxf(l, 0.0f) - l * t + log1pf(expf(-fabsf(l)));
            float w = 1.0f;
            if (t > 0.5f) {
                float e = 1.0f;
                const int x = x0 + j;
                for (int k = 0; k < 24; ++k) {
                    const int zz = z + OFFS[k][0];
                    const int yy = y + OFFS[k][1];
                    const int xx = x + OFFS[k][2];
                    float v = 0.0f;
                    if (((unsigned)zz < 128u) & ((unsigned)yy < 128u) & ((unsigned)xx < 128u))
                        v = tg[zz * HW_ + yy * WW + xx];
                    if (v < 0.5f) { e = 0.0f; break; }
                }
                w = 1.0f + 4.0f * (1.0f - e);
            }
            bce_local += bce * w;
        }
    }
    #pragma unroll
    for (int o = 32; o > 0; o >>= 1) {
        bce_local += __shfl_down(bce_local, o);
        n_local   += __shfl_down(n_local, o);
    }
    __shared__ float sb[4], sn[4];
    const int wave = tid >> 6;
    if ((tid & 63) == 0) { sb[wave] = bce_local; sn[wave] = n_local; }
    __syncthreads();
    if (tid == 0) {
        atomicAdd(&ws[0], (double)(sb[0] + sb[1] + sb[2] + sb[3]));
        atomicAdd(&ws[1], (double)(sn[0] + sn[1] + sn[2] + sn[3]));
    }
}

__global__ void bal_finalize_ws(const double* __restrict__ ws, float* __restrict__ out)
{
    const double s = ws[0];
    const double n = ws[1];
    out[0] = (n > 0.0) ? (float)(s / (n < 1.0 ? 1.0 : n)) : 0.0f;
}

extern "C" void kernel_launch(void* const* d_in, const int* in_sizes, int n_in,
                              void* d_out, int out_size, void* d_ws, size_t ws_size,
                              hipStream_t stream)
{
    const float* logits  = (const float*)d_in[0];
    const float* targets = (const float*)d_in[1];
    const int*   mask    = (const int*)d_in[2];
    const float* spatial = (const float*)d_in[3];
    float*       outp    = (float*)d_out;

    const size_t need = PK_BYTE_OFF + (size_t)8 * 32768 * sizeof(ull); // partials + 2 MB bits
    if (ws_size >= need) {
        ull*    pk = (ull*)((char*)d_ws + PK_BYTE_OFF);
        double* pr = (double*)d_ws;

        static int coop = -1;   // cached cooperative-launch capability
        if (coop < 0) {
            int dev = 0, v = 0;
            if (hipGetDevice(&dev) == hipSuccess &&
                hipDeviceGetAttribute(&v, hipDeviceAttributeCooperativeLaunch, dev) == hipSuccess)
                coop = v ? 1 : 0;
            else
                coop = 0;
        }
        if (coop) {
            void* args[] = { (void*)&logits, (void*)&targets, (void*)&spatial,
                             (void*)&mask, (void*)&pk, (void*)&pr, (void*)&outp };
            hipError_t e = hipLaunchCooperativeKernel((const void*)bal_fused,
                                                      dim3(1024), dim3(256),
                                                      args, 0, stream);
            if (e == hipSuccess) return;
            coop = 0;   // fall through to 3-kernel path (and stop retrying coop)
        }
        bal_pack<<<dim3(256, 8), 256, 0, stream>>>(targets, mask, pk);
        bal_main<<<dim3(512, 2), 256, 0, stream>>>(logits, spatial, mask, pk, pr);
        bal_finalize<<<1, 256, 0, stream>>>(pr, outp);
    } else {
        double* ws = (double*)d_ws;
        hipMemsetAsync(d_ws, 0, 16, stream);
        bal_direct<<<dim3(2048, 8), 256, 0, stream>>>(logits, targets, mask, spatial, ws);
        bal_finalize_ws<<<1, 1, 0, stream>>>(ws, outp);
    }
}